// Round 15
// baseline (600.129 us; speedup 1.0000x reference)
//
#include <hip/hip_runtime.h>
#include <hip/hip_bf16.h>
#include <stdint.h>

// ---------------------------------------------------------------------------
// QuantGRU: T=512, B=64, I=256, H=256. ACT scale 2^-7, W scale 2^-8.
// Fully exact integer arithmetic; sigmoid/tanh via 256-entry f64-built LUTs.
// R15: MFMA recurrence (R14, verified exact) with TRIPLE-CLOSURE tile
// assignment: wave w owns tiles {w,w+8,w+16,w+24,w+32,w+40} so each lane<16
// holds the full (sz,sr,sg) for 2 columns in-register -> gates run in-lane,
// Sbuf + barrier #1 are GONE. One light lgkm barrier per step (hq publish).
// ---------------------------------------------------------------------------

#define T_STEPS 512
#define BATCH   64
#define IDIM    256
#define HDIM    256
#define N3H     768   // 3*H

typedef int v4i __attribute__((ext_vector_type(4)));

#if defined(__has_builtin)
#if __has_builtin(__builtin_amdgcn_sdot4)
#define DOT4(a,b,c) __builtin_amdgcn_sdot4((int)(a),(int)(b),(int)(c),false)
#endif
#endif
#ifndef DOT4
__device__ __forceinline__ int dot4_sw(uint32_t a, uint32_t b, int c){
  c += (int)(int8_t)(a)      * (int)(int8_t)(b);
  c += (int)(int8_t)(a>>8)   * (int)(int8_t)(b>>8);
  c += (int)(int8_t)(a>>16)  * (int)(int8_t)(b>>16);
  c += (int)(int8_t)(a>>24)  * (int)(int8_t)(b>>24);
  return c;
}
#define DOT4(a,b,c) dot4_sw((uint32_t)(a),(uint32_t)(b),(int)(c))
#endif

// LDS-only workgroup barrier (no vmcnt drain; loads/stores stay in flight)
__device__ __forceinline__ void barrier_lds() {
  asm volatile("s_waitcnt lgkmcnt(0)\n\ts_barrier" ::: "memory");
}

// ---- exact integer round-to-nearest-even helpers (verified vs jnp.round) ---
__device__ __forceinline__ int clamp8(int x)   { return min(127, max(-128, x)); }
__device__ __forceinline__ int rne_half(int y) { int t = y >> 1; return t + (t & y & 1); }
__device__ __forceinline__ int rne_s8(int s)   { return (s + 127 + ((s >> 8) & 1)) >> 8; }
__device__ __forceinline__ int rne_s7(int p)   { return (p + 63 + ((p >> 7) & 1)) >> 7; }

// float RNE+clamp (quantize; used in prep/gemm only)
__device__ __forceinline__ int rneclamp(float v) {
  int q = (int)rintf(v);
  return min(127, max(-128, q));
}

__device__ __forceinline__ uint32_t packq4(float4 f, float sc) {
  uint32_t b0 = (uint32_t)(uint8_t)(int8_t)rneclamp(f.x * sc);
  uint32_t b1 = (uint32_t)(uint8_t)(int8_t)rneclamp(f.y * sc);
  uint32_t b2 = (uint32_t)(uint8_t)(int8_t)rneclamp(f.z * sc);
  uint32_t b3 = (uint32_t)(uint8_t)(int8_t)rneclamp(f.w * sc);
  return b0 | (b1 << 8) | (b2 << 16) | (b3 << 24);
}

// ---------------------------------------------------------------------------
// prep: W -> k-chunk-transposed int8 (for gemm_wx), R -> MFMA B-FRAGMENT
// layout: byte (((n*4+s)*64+l)*16+e) = R[k][col]*256, k=s*64+(l>>4)*16+e,
// col=n*16+(l&15)  (n=N-tile 0..47, s=K-slice 0..3, l=lane, e=byte).
// ---------------------------------------------------------------------------
__global__ void prep_kernel(const float* __restrict__ W, const float* __restrict__ R,
                            const float* __restrict__ bx, const float* __restrict__ br,
                            int8_t* __restrict__ Wq, int8_t* __restrict__ BF,
                            int8_t* __restrict__ bx8, int8_t* __restrict__ br8) {
  const int NW = IDIM * N3H; // 196608
  int idx = blockIdx.x * 256 + threadIdx.x;
  if (idx < NW) {
    int k = idx / N3H, j = idx % N3H;
    Wq[((size_t)(k >> 4) * N3H + j) * 16 + (k & 15)] = (int8_t)rneclamp(W[idx] * 256.0f);
  } else if (idx < 2 * NW) {
    int i2 = idx - NW;               // linear index into BF
    int e = i2 & 15;
    int l = (i2 >> 4) & 63;
    int s = (i2 >> 10) & 3;
    int n = i2 >> 12;                // 0..47
    int k   = s * 64 + ((l >> 4) << 4) + e;
    int col = n * 16 + (l & 15);
    BF[i2] = (int8_t)rneclamp(R[(size_t)k * N3H + col] * 256.0f);
  } else if (idx < 2 * NW + N3H) {
    int i2 = idx - 2 * NW;
    bx8[i2] = (int8_t)rneclamp(bx[i2] * 256.0f);
  } else if (idx < 2 * NW + 2 * N3H) {
    int i2 = idx - 2 * NW - N3H;
    br8[i2] = (int8_t)rneclamp(br[i2] * 256.0f);
  }
}

// ---------------------------------------------------------------------------
// gemm_wx: Wx_q[b][t][j] = clamp(rne( (fq(x) . Wq col j) / 256 ))  (int8)
// one block per t (64 rows), 768 threads = one per output column.
// ---------------------------------------------------------------------------
__global__ __launch_bounds__(768, 1) void gemm_wx_kernel(
    const float* __restrict__ x, const int8_t* __restrict__ Wq,
    int8_t* __restrict__ WxQ8) {
  const int t = blockIdx.x;   // 0..511
  const int j = threadIdx.x;  // 0..767

  __shared__ uint4 xq4[64 * 16];   // 64 rows x 256 int8 = 16KB
  uint32_t* xq = (uint32_t*)xq4;

  uint4 w[16];
  const uint4* wp = (const uint4*)Wq;
  #pragma unroll
  for (int kk = 0; kk < 16; ++kk) w[kk] = wp[kk * N3H + j];

  const float4* xg = (const float4*)(x) + (size_t)t * 4096;
  for (int i = j; i < 4096; i += 768) {
    float4 f = xg[i];
    xq[i] = packq4(f, 128.0f);
  }
  __syncthreads();

  for (int r = 0; r < 64; ++r) {
    int s = 0;
    #pragma unroll
    for (int kk = 0; kk < 16; ++kk) {
      uint4 hv = xq4[r * 16 + kk];
      s = DOT4(hv.x, w[kk].x, s);
      s = DOT4(hv.y, w[kk].y, s);
      s = DOT4(hv.z, w[kk].z, s);
      s = DOT4(hv.w, w[kk].w, s);
    }
    int q = clamp8(rne_s8(s));
    WxQ8[((size_t)r * T_STEPS + t) * N3H + j] = (int8_t)q;
  }
}

// ---------------------------------------------------------------------------
// gru_rec15: one block per batch; 512 threads = 8 waves.
// Wave w: tiles {w, w+8, w+16, w+24, w+32, w+40} -> lane l<16 holds triples
// for cols 16w+l and 128+16w+l entirely in-register. One barrier/step.
// ---------------------------------------------------------------------------
__global__ __launch_bounds__(512, 1)
void gru_rec15_kernel(
    const float* __restrict__ h0, const int8_t* __restrict__ BF,
    const int8_t* __restrict__ bx8, const int8_t* __restrict__ br8,
    const int8_t* __restrict__ WxQ8, float* __restrict__ out) {
  const int b    = blockIdx.x;      // batch element
  const int tid  = threadIdx.x;     // 0..511
  const int lane = tid & 63;
  const int wave = tid >> 6;        // 0..7

  __shared__ alignas(16) int8_t hq[2][256];   // int8 h (row 0 of A)
  __shared__ int8_t lutS[256];
  __shared__ int8_t lutT[256];

  // B fragments: triple-closure tiles {w, w+8, w+16, w+24, w+32, w+40}
  v4i bf[6][4];
  {
    const v4i* bp = (const v4i*)BF;
    #pragma unroll
    for (int i = 0; i < 6; ++i) {
      int n = wave + (i & 1) * 8 + (i >> 1) * 16;
      #pragma unroll
      for (int s = 0; s < 4; ++s)
        bf[i][s] = bp[(n * 4 + s) * 64 + lane];
    }
  }

  // LUT + hq init (threads 0-255)
  if (tid < 256) {
    double a = ((double)tid - 128.0) / 128.0;
    lutS[tid] = (int8_t)min(127, max(-128, (int)rint(128.0 / (1.0 + exp(-a)))));
    lutT[tid] = (int8_t)min(127, max(-128, (int)rint(128.0 * tanh(a))));
    int h00 = (int)rintf(h0[b * HDIM + tid] * 128.0f);
    hq[0][tid] = (int8_t)clamp8(h00);
  }

  // gate-lane state (lane < 16): columns col0, col1
  const int col0 = wave * 16 + (lane & 15);
  const int col1 = col0 + 128;
  int hi0 = 0, hi1 = 0;
  int bz0 = 0, br0 = 0, bg0 = 0, vz0b = 0, vr0b = 0, vg0b = 0;
  int bz1 = 0, br1 = 0, bg1 = 0, vz1b = 0, vr1b = 0, vg1b = 0;
  const int8_t* wxb = WxQ8 + (size_t)b * T_STEPS * N3H;
  int z0A = 0, r0A = 0, g0A = 0, z1A = 0, r1A = 0, g1A = 0;
  int z0B = 0, r0B = 0, g0B = 0, z1B = 0, r1B = 0, g1B = 0;
  if (lane < 16) {
    bz0 = (int)bx8[col0]; br0 = (int)bx8[col0 + 256]; bg0 = (int)bx8[col0 + 512];
    vz0b = (int)br8[col0]; vr0b = (int)br8[col0 + 256]; vg0b = (int)br8[col0 + 512];
    bz1 = (int)bx8[col1]; br1 = (int)bx8[col1 + 256]; bg1 = (int)bx8[col1 + 512];
    vz1b = (int)br8[col1]; vr1b = (int)br8[col1 + 256]; vg1b = (int)br8[col1 + 512];
    hi0 = (int)rintf(h0[b * HDIM + col0] * 128.0f);
    hi1 = (int)rintf(h0[b * HDIM + col1] * 128.0f);
    // Wx 2-deep prefetch: step 0 (A) and step 1 (B)
    z0A = (int)wxb[col0]; r0A = (int)wxb[col0 + 256]; g0A = (int)wxb[col0 + 512];
    z1A = (int)wxb[col1]; r1A = (int)wxb[col1 + 256]; g1A = (int)wxb[col1 + 512];
    z0B = (int)wxb[N3H + col0]; r0B = (int)wxb[N3H + col0 + 256]; g0B = (int)wxb[N3H + col0 + 512];
    z1B = (int)wxb[N3H + col1]; r1B = (int)wxb[N3H + col1 + 256]; g1B = (int)wxb[N3H + col1 + 512];
  }
  __syncthreads();

  float* outp0 = out + (size_t)b * HDIM + col0;
  float* outp1 = out + (size_t)b * HDIM + col1;
  const int kg = (lane >> 4) << 4;   // 0,16,32,48 within each 64-wide K-slice

  for (int t = 0; t < T_STEPS; ++t) {
    const int cur = t & 1, nxt = cur ^ 1;

    // issue Wx loads for t+2 (gate lanes; 2 steps of latency hiding)
    int nz0 = 0, nr0 = 0, ng0 = 0, nz1 = 0, nr1 = 0, ng1 = 0;
    if (lane < 16) {
      const int8_t* p = wxb + (size_t)min(t + 2, T_STEPS - 1) * N3H;
      nz0 = (int)p[col0]; nr0 = (int)p[col0 + 256]; ng0 = (int)p[col0 + 512];
      nz1 = (int)p[col1]; nr1 = (int)p[col1 + 256]; ng1 = (int)p[col1 + 512];
    }

    // ---- A fragments from hq row (rows 1-15 duplicates; harmless)
    v4i a0 = *(const v4i*)&hq[cur][  0 + kg];
    v4i a1 = *(const v4i*)&hq[cur][ 64 + kg];
    v4i a2 = *(const v4i*)&hq[cur][128 + kg];
    v4i a3 = *(const v4i*)&hq[cur][192 + kg];

    // ---- MFMA: 6 tiles, 2 accumulation chains each (halved latency)
    int s_[6];
    #pragma unroll
    for (int i = 0; i < 6; ++i) {
      v4i za = {0, 0, 0, 0}, zb = {0, 0, 0, 0};
      za = __builtin_amdgcn_mfma_i32_16x16x64_i8(a0, bf[i][0], za, 0, 0, 0);
      zb = __builtin_amdgcn_mfma_i32_16x16x64_i8(a2, bf[i][2], zb, 0, 0, 0);
      za = __builtin_amdgcn_mfma_i32_16x16x64_i8(a1, bf[i][1], za, 0, 0, 0);
      zb = __builtin_amdgcn_mfma_i32_16x16x64_i8(a3, bf[i][3], zb, 0, 0, 0);
      s_[i] = za[0] + zb[0];       // row 0 (reg 0, lanes 0-15)
    }

    // ---- gates fully in-lane (lanes 0-15 of every wave), exact integer ----
    if (lane < 16) {
      // column col0: triple in s_[0], s_[2], s_[4]
      {
        int vz = clamp8(rne_half(2 * clamp8(rne_s8(s_[0])) + vz0b));
        int vr = clamp8(rne_half(2 * clamp8(rne_s8(s_[2])) + vr0b));
        int vg = clamp8(rne_half(2 * clamp8(rne_s8(s_[4])) + vg0b));
        int az = clamp8(rne_half(2 * (z0A + vz) + bz0));
        int zi = (int)lutS[az + 128];
        int ar = clamp8(rne_half(2 * (r0A + vr) + br0));
        int ri = (int)lutS[ar + 128];
        int rrh = clamp8(rne_s7(ri * vg));
        int ag = clamp8(rne_half(2 * (g0A + rrh) + bg0));
        int gi = (int)lutT[ag + 128];
        int oldi = clamp8(rne_s7(zi * hi0));
        int newi = clamp8(rne_s7((128 - zi) * gi));
        hi0 = oldi + newi;
        outp0[(size_t)t * BATCH * HDIM] = (float)hi0 * (1.0f / 128.0f);
        hq[nxt][col0] = (int8_t)clamp8(hi0);
        z0A = z0B; r0A = r0B; g0A = g0B;
        z0B = nz0; r0B = nr0; g0B = ng0;
      }
      // column col1: triple in s_[1], s_[3], s_[5]
      {
        int vz = clamp8(rne_half(2 * clamp8(rne_s8(s_[1])) + vz1b));
        int vr = clamp8(rne_half(2 * clamp8(rne_s8(s_[3])) + vr1b));
        int vg = clamp8(rne_half(2 * clamp8(rne_s8(s_[5])) + vg1b));
        int az = clamp8(rne_half(2 * (z1A + vz) + bz1));
        int zi = (int)lutS[az + 128];
        int ar = clamp8(rne_half(2 * (r1A + vr) + br1));
        int ri = (int)lutS[ar + 128];
        int rrh = clamp8(rne_s7(ri * vg));
        int ag = clamp8(rne_half(2 * (g1A + rrh) + bg1));
        int gi = (int)lutT[ag + 128];
        int oldi = clamp8(rne_s7(zi * hi1));
        int newi = clamp8(rne_s7((128 - zi) * gi));
        hi1 = oldi + newi;
        outp1[(size_t)t * BATCH * HDIM] = (float)hi1 * (1.0f / 128.0f);
        hq[nxt][col1] = (int8_t)clamp8(hi1);
        z1A = z1B; r1A = r1B; g1A = g1B;
        z1B = nz1; r1B = nr1; g1B = ng1;
      }
    }
    barrier_lds();   // hq[nxt] published; vmcnt stays in flight
  }
}

// ---------------------------------------------------------------------------
extern "C" void kernel_launch(void* const* d_in, const int* in_sizes, int n_in,
                              void* d_out, int out_size, void* d_ws, size_t ws_size,
                              hipStream_t stream) {
  const float* x  = (const float*)d_in[0];   // (T,B,I)
  const float* h0 = (const float*)d_in[1];   // (B,H)
  const float* W  = (const float*)d_in[2];   // (I,3H)
  const float* R  = (const float*)d_in[3];   // (H,3H)
  const float* bx = (const float*)d_in[4];   // (3H,)
  const float* br = (const float*)d_in[5];   // (3H,)
  float* out = (float*)d_out;                // (T,B,H)

  // workspace layout
  const size_t NW = (size_t)IDIM * N3H;          // 196608
  int8_t* Wq  = (int8_t*)d_ws;                   // 196608
  int8_t* BF  = Wq + NW;                         // 196608 (R as MFMA B-frags)
  int8_t* bx8 = BF + NW;                         // 768
  int8_t* br8 = bx8 + N3H;                       // 768
  int8_t* WxQ8 = br8 + N3H;                      // 64*512*768 = 25165824

  {
    int total = (int)(2 * NW + 2 * N3H);
    int blocks = (total + 255) / 256;
    prep_kernel<<<blocks, 256, 0, stream>>>(W, R, bx, br, Wq, BF, bx8, br8);
  }
  gemm_wx_kernel<<<T_STEPS, 768, 0, stream>>>(x, Wq, WxQ8);
  gru_rec15_kernel<<<BATCH, 512, 0, stream>>>(h0, BF, bx8, br8, WxQ8, out);
}

// Round 16
// 519.774 us; speedup vs baseline: 1.1546x; 1.1546x over previous
//
#include <hip/hip_runtime.h>
#include <hip/hip_bf16.h>
#include <stdint.h>

// ---------------------------------------------------------------------------
// QuantGRU: T=512, B=64, I=256, H=256. ACT scale 2^-7, W scale 2^-8.
// Fully exact integer arithmetic; sigmoid/tanh via 256-entry f64-built LUTs.
// R16: R14 MFMA recurrence (verified exact) + B-fragments PINNED IN AGPRs
// ("+a" asm touch inside the t-loop). R5-R15 post-mortems converged on one
// wall: ~196KB of weights re-streamed from L1 every step (~1500 cyc) because
// the allocator never keeps them resident and v_dot4 can't read AGPRs.
// MFMA CAN read AGPRs (AV_* operand classes) -- so park the weights there,
// pin them so remat is illegal, and the per-step weight traffic vanishes.
// ---------------------------------------------------------------------------

#define T_STEPS 512
#define BATCH   64
#define IDIM    256
#define HDIM    256
#define N3H     768   // 3*H

typedef int v4i __attribute__((ext_vector_type(4)));

#if defined(__has_builtin)
#if __has_builtin(__builtin_amdgcn_sdot4)
#define DOT4(a,b,c) __builtin_amdgcn_sdot4((int)(a),(int)(b),(int)(c),false)
#endif
#endif
#ifndef DOT4
__device__ __forceinline__ int dot4_sw(uint32_t a, uint32_t b, int c){
  c += (int)(int8_t)(a)      * (int)(int8_t)(b);
  c += (int)(int8_t)(a>>8)   * (int)(int8_t)(b>>8);
  c += (int)(int8_t)(a>>16)  * (int)(int8_t)(b>>16);
  c += (int)(int8_t)(a>>24)  * (int)(int8_t)(b>>24);
  return c;
}
#define DOT4(a,b,c) dot4_sw((uint32_t)(a),(uint32_t)(b),(int)(c))
#endif

// LDS-only workgroup barrier (no vmcnt drain; loads/stores stay in flight)
__device__ __forceinline__ void barrier_lds() {
  asm volatile("s_waitcnt lgkmcnt(0)\n\ts_barrier" ::: "memory");
}

// ---- exact integer round-to-nearest-even helpers (verified vs jnp.round) ---
__device__ __forceinline__ int clamp8(int x)   { return min(127, max(-128, x)); }
__device__ __forceinline__ int rne_half(int y) { int t = y >> 1; return t + (t & y & 1); }
__device__ __forceinline__ int rne_s8(int s)   { return (s + 127 + ((s >> 8) & 1)) >> 8; }
__device__ __forceinline__ int rne_s7(int p)   { return (p + 63 + ((p >> 7) & 1)) >> 7; }

// float RNE+clamp (quantize; used in prep/gemm only)
__device__ __forceinline__ int rneclamp(float v) {
  int q = (int)rintf(v);
  return min(127, max(-128, q));
}

__device__ __forceinline__ uint32_t packq4(float4 f, float sc) {
  uint32_t b0 = (uint32_t)(uint8_t)(int8_t)rneclamp(f.x * sc);
  uint32_t b1 = (uint32_t)(uint8_t)(int8_t)rneclamp(f.y * sc);
  uint32_t b2 = (uint32_t)(uint8_t)(int8_t)rneclamp(f.z * sc);
  uint32_t b3 = (uint32_t)(uint8_t)(int8_t)rneclamp(f.w * sc);
  return b0 | (b1 << 8) | (b2 << 16) | (b3 << 24);
}

// ---------------------------------------------------------------------------
// prep: W -> k-chunk-transposed int8 (for gemm_wx), R -> MFMA B-FRAGMENT
// layout: byte (((n*4+s)*64+l)*16+e) = R[k][col]*256, k=s*64+(l>>4)*16+e,
// col=n*16+(l&15)  (n=N-tile 0..47, s=K-slice 0..3, l=lane, e=byte).
// ---------------------------------------------------------------------------
__global__ void prep_kernel(const float* __restrict__ W, const float* __restrict__ R,
                            const float* __restrict__ bx, const float* __restrict__ br,
                            int8_t* __restrict__ Wq, int8_t* __restrict__ BF,
                            int8_t* __restrict__ bx8, int8_t* __restrict__ br8) {
  const int NW = IDIM * N3H; // 196608
  int idx = blockIdx.x * 256 + threadIdx.x;
  if (idx < NW) {
    int k = idx / N3H, j = idx % N3H;
    Wq[((size_t)(k >> 4) * N3H + j) * 16 + (k & 15)] = (int8_t)rneclamp(W[idx] * 256.0f);
  } else if (idx < 2 * NW) {
    int i2 = idx - NW;               // linear index into BF
    int e = i2 & 15;
    int l = (i2 >> 4) & 63;
    int s = (i2 >> 10) & 3;
    int n = i2 >> 12;                // 0..47
    int k   = s * 64 + ((l >> 4) << 4) + e;
    int col = n * 16 + (l & 15);
    BF[i2] = (int8_t)rneclamp(R[(size_t)k * N3H + col] * 256.0f);
  } else if (idx < 2 * NW + N3H) {
    int i2 = idx - 2 * NW;
    bx8[i2] = (int8_t)rneclamp(bx[i2] * 256.0f);
  } else if (idx < 2 * NW + 2 * N3H) {
    int i2 = idx - 2 * NW - N3H;
    br8[i2] = (int8_t)rneclamp(br[i2] * 256.0f);
  }
}

// ---------------------------------------------------------------------------
// gemm_wx: Wx_q[b][t][j] = clamp(rne( (fq(x) . Wq col j) / 256 ))  (int8)
// one block per t (64 rows), 768 threads = one per output column.
// ---------------------------------------------------------------------------
__global__ __launch_bounds__(768, 1) void gemm_wx_kernel(
    const float* __restrict__ x, const int8_t* __restrict__ Wq,
    int8_t* __restrict__ WxQ8) {
  const int t = blockIdx.x;   // 0..511
  const int j = threadIdx.x;  // 0..767

  __shared__ uint4 xq4[64 * 16];   // 64 rows x 256 int8 = 16KB
  uint32_t* xq = (uint32_t*)xq4;

  uint4 w[16];
  const uint4* wp = (const uint4*)Wq;
  #pragma unroll
  for (int kk = 0; kk < 16; ++kk) w[kk] = wp[kk * N3H + j];

  const float4* xg = (const float4*)(x) + (size_t)t * 4096;
  for (int i = j; i < 4096; i += 768) {
    float4 f = xg[i];
    xq[i] = packq4(f, 128.0f);
  }
  __syncthreads();

  for (int r = 0; r < 64; ++r) {
    int s = 0;
    #pragma unroll
    for (int kk = 0; kk < 16; ++kk) {
      uint4 hv = xq4[r * 16 + kk];
      s = DOT4(hv.x, w[kk].x, s);
      s = DOT4(hv.y, w[kk].y, s);
      s = DOT4(hv.z, w[kk].z, s);
      s = DOT4(hv.w, w[kk].w, s);
    }
    int q = clamp8(rne_s8(s));
    WxQ8[((size_t)r * T_STEPS + t) * N3H + j] = (int8_t)q;
  }
}

// ---------------------------------------------------------------------------
// gru_rec16: one block per batch; 512 threads = 8 waves (2/SIMD).
// All waves: MFMA S = hq @ R (6 N-tiles each), B-fragments AGPR-pinned.
// Threads 0-255: exact gate tail (verbatim R6/R14).
// ---------------------------------------------------------------------------
__global__ __launch_bounds__(512, 2)
void gru_rec16_kernel(
    const float* __restrict__ h0, const int8_t* __restrict__ BF,
    const int8_t* __restrict__ bx8, const int8_t* __restrict__ br8,
    const int8_t* __restrict__ WxQ8, float* __restrict__ out) {
  const int b    = blockIdx.x;      // batch element
  const int tid  = threadIdx.x;     // 0..511
  const int lane = tid & 63;
  const int wave = tid >> 6;        // 0..7
  const int j    = tid & 255;       // gate index (tid<256)

  __shared__ alignas(16) int8_t hq[2][256];   // int8 h (row 0 of A)
  __shared__ int    Sbuf[N3H];                // raw i32 GEMV results
  __shared__ int8_t lutS[256];
  __shared__ int8_t lutT[256];

  // B fragments: 6 N-tiles x 4 K-slices -> live in AGPRs (pinned in-loop)
  v4i bf[6][4];
  {
    const v4i* bp = (const v4i*)BF;
    #pragma unroll
    for (int i = 0; i < 6; ++i)
      #pragma unroll
      for (int s = 0; s < 4; ++s)
        bf[i][s] = bp[((wave * 6 + i) * 4 + s) * 64 + lane];
  }

  // gate-thread state (tid < 256)
  int hi = 0, bzc = 0, brc = 0, bgc = 0, vbz = 0, vbr = 0, vbg = 0;
  const int8_t* wxp = WxQ8 + (size_t)b * T_STEPS * N3H + j;
  int wxA0 = 0, wxA1 = 0, wxA2 = 0, wxB0 = 0, wxB1 = 0, wxB2 = 0;
  if (tid < 256) {
    double a = ((double)j - 128.0) / 128.0;
    lutS[j] = (int8_t)min(127, max(-128, (int)rint(128.0 / (1.0 + exp(-a)))));
    lutT[j] = (int8_t)min(127, max(-128, (int)rint(128.0 * tanh(a))));
    bzc = (int)bx8[j];
    brc = (int)bx8[j + 256];
    bgc = (int)bx8[j + 512];
    vbz = (int)br8[j];
    vbr = (int)br8[j + 256];
    vbg = (int)br8[j + 512];
    hi = (int)rintf(h0[b * HDIM + j] * 128.0f);   // exact int, units 1/128
    hq[0][j] = (int8_t)clamp8(hi);
    wxA0 = (int)wxp[0];   wxA1 = (int)wxp[256];       wxA2 = (int)wxp[512];
    wxB0 = (int)wxp[N3H]; wxB1 = (int)wxp[N3H + 256]; wxB2 = (int)wxp[N3H + 512];
  }
  __syncthreads();

  float* outp = out + (size_t)b * HDIM + j;
  const int kg = (lane >> 4) << 4;   // 0,16,32,48 within each 64-wide K-slice

  for (int t = 0; t < T_STEPS; ++t) {
    const int cur = t & 1, nxt = cur ^ 1;

    // Pin B-fragments to AGPRs each iteration: asm "may modify" makes
    // rematerialization from memory illegal; MFMA reads AGPRs natively.
    #pragma unroll
    for (int i = 0; i < 6; ++i)
      asm volatile("" : "+a"(bf[i][0]), "+a"(bf[i][1]), "+a"(bf[i][2]), "+a"(bf[i][3]));

    // issue Wx loads for t+2 (gate threads)
    int nz = 0, nr = 0, ng = 0;
    if (tid < 256) {
      const int8_t* p = wxp + (size_t)min(t + 2, T_STEPS - 1) * N3H;
      nz = (int)p[0]; nr = (int)p[256]; ng = (int)p[512];
    }

    // ---- A fragments from hq row (rows 1-15 of A are duplicates; harmless)
    v4i a0 = *(const v4i*)&hq[cur][  0 + kg];
    v4i a1 = *(const v4i*)&hq[cur][ 64 + kg];
    v4i a2 = *(const v4i*)&hq[cur][128 + kg];
    v4i a3 = *(const v4i*)&hq[cur][192 + kg];

    // ---- MFMA: 6 tiles x 4 K-slices
    v4i acc[6];
    #pragma unroll
    for (int i = 0; i < 6; ++i) {
      v4i z = {0, 0, 0, 0};
      z = __builtin_amdgcn_mfma_i32_16x16x64_i8(a0, bf[i][0], z, 0, 0, 0);
      z = __builtin_amdgcn_mfma_i32_16x16x64_i8(a1, bf[i][1], z, 0, 0, 0);
      z = __builtin_amdgcn_mfma_i32_16x16x64_i8(a2, bf[i][2], z, 0, 0, 0);
      z = __builtin_amdgcn_mfma_i32_16x16x64_i8(a3, bf[i][3], z, 0, 0, 0);
      acc[i] = z;
    }
    // ---- extract row 0: col=lane&15, row=(lane>>4)*4+reg => lanes 0-15, reg 0
    if (lane < 16) {
      #pragma unroll
      for (int i = 0; i < 6; ++i)
        Sbuf[(wave * 6 + i) * 16 + lane] = acc[i][0];
    }
    barrier_lds();   // #1: Sbuf ready

    // ---- gate tail (threads 0-255), exact integer (verbatim R6) ----
    if (tid < 256) {
      int sz = Sbuf[j], sr = Sbuf[j + 256], sg = Sbuf[j + 512];
      int vz = clamp8(rne_half(2 * clamp8(rne_s8(sz)) + vbz));
      int vr = clamp8(rne_half(2 * clamp8(rne_s8(sr)) + vbr));
      int vg = clamp8(rne_half(2 * clamp8(rne_s8(sg)) + vbg));
      int az = clamp8(rne_half(2 * (wxA0 + vz) + bzc));
      int zi = (int)lutS[az + 128];
      int ar = clamp8(rne_half(2 * (wxA1 + vr) + brc));
      int ri = (int)lutS[ar + 128];
      int rrh = clamp8(rne_s7(ri * vg));
      int ag = clamp8(rne_half(2 * (wxA2 + rrh) + bgc));
      int gi = (int)lutT[ag + 128];
      int oldi = clamp8(rne_s7(zi * hi));
      int newi = clamp8(rne_s7((128 - zi) * gi));
      hi = oldi + newi;                       // integer, units 1/128
      outp[(size_t)t * BATCH * HDIM] = (float)hi * (1.0f / 128.0f);
      hq[nxt][j] = (int8_t)clamp8(hi);
      wxA0 = wxB0; wxA1 = wxB1; wxA2 = wxB2;
      wxB0 = nz;   wxB1 = nr;   wxB2 = ng;
    }
    barrier_lds();   // #2: hq[nxt] published
  }
}

// ---------------------------------------------------------------------------
extern "C" void kernel_launch(void* const* d_in, const int* in_sizes, int n_in,
                              void* d_out, int out_size, void* d_ws, size_t ws_size,
                              hipStream_t stream) {
  const float* x  = (const float*)d_in[0];   // (T,B,I)
  const float* h0 = (const float*)d_in[1];   // (B,H)
  const float* W  = (const float*)d_in[2];   // (I,3H)
  const float* R  = (const float*)d_in[3];   // (H,3H)
  const float* bx = (const float*)d_in[4];   // (3H,)
  const float* br = (const float*)d_in[5];   // (3H,)
  float* out = (float*)d_out;                // (T,B,H)

  // workspace layout
  const size_t NW = (size_t)IDIM * N3H;          // 196608
  int8_t* Wq  = (int8_t*)d_ws;                   // 196608
  int8_t* BF  = Wq + NW;                         // 196608 (R as MFMA B-frags)
  int8_t* bx8 = BF + NW;                         // 768
  int8_t* br8 = bx8 + N3H;                       // 768
  int8_t* WxQ8 = br8 + N3H;                      // 64*512*768 = 25165824

  {
    int total = (int)(2 * NW + 2 * N3H);
    int blocks = (total + 255) / 256;
    prep_kernel<<<blocks, 256, 0, stream>>>(W, R, bx, br, Wq, BF, bx8, br8);
  }
  gemm_wx_kernel<<<T_STEPS, 768, 0, stream>>>(x, Wq, WxQ8);
  gru_rec16_kernel<<<BATCH, 512, 0, stream>>>(h0, BF, bx8, br8, WxQ8, out);
}